// Round 1
// baseline (766.672 us; speedup 1.0000x reference)
//
#include <hip/hip_runtime.h>
#include <math.h>

#define NB 2
#define TT 10
#define NN 1024
#define DD 1024
#define NHH 16
#define HDD 64
#define BTT 20   // B*T

// ws offsets in floats
#define TRAJ_OFF 0
#define Q_OFF    1048576            // N*N
#define K_OFF    (Q_OFF + 2097152)  // + B*N*D
#define V_OFF    (K_OFF + 2097152)
#define AO_OFF   (V_OFF + 2097152)
#define L_OFF    (AO_OFF + 2097152) // B*NH*N floats

#define HMAXL 6.93147180559945f     // log(1024)

// ---------------------------------------------------------------------------
// traj[i,j] = exp(-mean_bt||pi-pj|| - min(mean||qi-qj||, mean||qi+qj||)), row-normalized
__global__ __launch_bounds__(256) void traj_kernel(const float* __restrict__ pos,
                                                   const float* __restrict__ quat,
                                                   float* __restrict__ traj) {
  const int i = blockIdx.x;
  const int tid = threadIdx.x;
  __shared__ float pi[BTT][3];
  __shared__ float qi[BTT][4];
  __shared__ float red[256];
  if (tid < BTT * 3) pi[tid / 3][tid % 3] = pos[((size_t)(tid / 3) * NN + i) * 3 + (tid % 3)];
  if (tid < BTT * 4) qi[tid / 4][tid % 4] = quat[((size_t)(tid / 4) * NN + i) * 4 + (tid % 4)];
  __syncthreads();
  float vj[4];
  float rs = 0.f;
  for (int jt = 0; jt < 4; ++jt) {
    int j = tid + jt * 256;
    float pd = 0.f, qm = 0.f, qp = 0.f;
    for (int bt = 0; bt < BTT; ++bt) {
      const float* pj = pos + ((size_t)bt * NN + j) * 3;
      float dx = pi[bt][0] - pj[0], dy = pi[bt][1] - pj[1], dz = pi[bt][2] - pj[2];
      pd += sqrtf(dx * dx + dy * dy + dz * dz);
      float4 qj = *(const float4*)(quat + ((size_t)bt * NN + j) * 4);
      float a0 = qi[bt][0], a1 = qi[bt][1], a2 = qi[bt][2], a3 = qi[bt][3];
      float m0 = a0 - qj.x, m1 = a1 - qj.y, m2 = a2 - qj.z, m3 = a3 - qj.w;
      float p0 = a0 + qj.x, p1 = a1 + qj.y, p2 = a2 + qj.z, p3 = a3 + qj.w;
      qm += sqrtf(m0 * m0 + m1 * m1 + m2 * m2 + m3 * m3);
      qp += sqrtf(p0 * p0 + p1 * p1 + p2 * p2 + p3 * p3);
    }
    float v = expf(-(pd + fminf(qm, qp)) * (1.f / BTT));
    vj[jt] = v;
    rs += v;
  }
  red[tid] = rs;
  __syncthreads();
  for (int s = 128; s > 0; s >>= 1) {
    if (tid < s) red[tid] += red[tid + s];
    __syncthreads();
  }
  float inv = 1.f / red[0];
  for (int jt = 0; jt < 4; ++jt)
    traj[(size_t)i * NN + tid + jt * 256] = vj[jt] * inv;
}

// ---------------------------------------------------------------------------
// C[M,Nc] = A[M,Kc] @ W[Nc,Kc]^T + bias   (all dims multiples of 64)
__global__ __launch_bounds__(256) void gemm_abt_kernel(const float* __restrict__ A,
                                                       const float* __restrict__ W,
                                                       const float* __restrict__ bias,
                                                       float* __restrict__ C,
                                                       int M, int Nc, int Kc) {
  __shared__ float As[16][68];  // [k][m]
  __shared__ float Ws[16][68];  // [k][n]
  const int tid = threadIdx.x;
  const int bm = blockIdx.y << 6, bn = blockIdx.x << 6;
  const int tx = tid & 15, ty = tid >> 4;
  const int lr = tid >> 2, lk = (tid & 3) << 2;
  float acc[4][4] = {};
  for (int k0 = 0; k0 < Kc; k0 += 16) {
    float4 a4 = *(const float4*)(A + (size_t)(bm + lr) * Kc + k0 + lk);
    float4 w4 = *(const float4*)(W + (size_t)(bn + lr) * Kc + k0 + lk);
    __syncthreads();
    As[lk + 0][lr] = a4.x; As[lk + 1][lr] = a4.y; As[lk + 2][lr] = a4.z; As[lk + 3][lr] = a4.w;
    Ws[lk + 0][lr] = w4.x; Ws[lk + 1][lr] = w4.y; Ws[lk + 2][lr] = w4.z; Ws[lk + 3][lr] = w4.w;
    __syncthreads();
#pragma unroll
    for (int k = 0; k < 16; ++k) {
      float4 av = *(const float4*)&As[k][ty << 2];
      float4 wv = *(const float4*)&Ws[k][tx << 2];
      float avv[4] = {av.x, av.y, av.z, av.w};
      float wvv[4] = {wv.x, wv.y, wv.z, wv.w};
#pragma unroll
      for (int r = 0; r < 4; ++r)
#pragma unroll
        for (int c = 0; c < 4; ++c)
          acc[r][c] += avv[r] * wvv[c];
    }
  }
  float4 b4 = *(const float4*)(bias + bn + (tx << 2));
  float bb[4] = {b4.x, b4.y, b4.z, b4.w};
#pragma unroll
  for (int r = 0; r < 4; ++r) {
    float4 ov = make_float4(acc[r][0] + bb[0], acc[r][1] + bb[1],
                            acc[r][2] + bb[2], acc[r][3] + bb[3]);
    *(float4*)(C + (size_t)(bm + (ty << 2) + r) * Nc + bn + (tx << 2)) = ov;
  }
}

// ---------------------------------------------------------------------------
// Fused attention per (b,h): AO[b,i,h*64+d] = softmax(QK^T/8 + 0.5*traj) @ V
// Also stores softmax denominators Lv[(b*NH+h)*N + i] (no-max softmax; scores bounded ~|6|).
__global__ __launch_bounds__(256) void att_kernel(const float* __restrict__ Q,
                                                  const float* __restrict__ K,
                                                  const float* __restrict__ V,
                                                  const float* __restrict__ traj,
                                                  float* __restrict__ AO,
                                                  float* __restrict__ Lv) {
  const int tid = threadIdx.x;
  const int bh = blockIdx.y;
  const int b = bh >> 4, h = bh & 15;
  const int i0 = blockIdx.x << 6;
  const int tx = tid & 15, ty = tid >> 4;
  __shared__ float Qs[HDD][68];  // [k][i]
  __shared__ float Ks[HDD][68];  // [k][j]
  __shared__ float Vs[64][68];   // [j][d]
  __shared__ float Ss[64][68];   // [j][i]  (exp'd scores)
  __shared__ float lred[64][17];
  __shared__ float lsc[64];
  const int r0 = tid >> 4;
  const int c4 = (tid & 15) << 2;
  // stage Q tile transposed
#pragma unroll
  for (int rep = 0; rep < 4; ++rep) {
    int i = r0 + (rep << 4);
    float4 q4 = *(const float4*)(Q + ((size_t)(b * NN) + i0 + i) * DD + h * HDD + c4);
    Qs[c4 + 0][i] = q4.x; Qs[c4 + 1][i] = q4.y; Qs[c4 + 2][i] = q4.z; Qs[c4 + 3][i] = q4.w;
  }
  float o[4][4] = {};
  float lacc = 0.f;  // owner threads (tid<64) accumulate l for i=tid
  for (int j0 = 0; j0 < NN; j0 += 64) {
    float4 kk4[4], vv4[4];
#pragma unroll
    for (int rep = 0; rep < 4; ++rep) {
      int j = r0 + (rep << 4);
      kk4[rep] = *(const float4*)(K + ((size_t)(b * NN) + j0 + j) * DD + h * HDD + c4);
      vv4[rep] = *(const float4*)(V + ((size_t)(b * NN) + j0 + j) * DD + h * HDD + c4);
    }
    __syncthreads();  // previous iter's PV / S reads done
#pragma unroll
    for (int rep = 0; rep < 4; ++rep) {
      int j = r0 + (rep << 4);
      Ks[c4 + 0][j] = kk4[rep].x; Ks[c4 + 1][j] = kk4[rep].y;
      Ks[c4 + 2][j] = kk4[rep].z; Ks[c4 + 3][j] = kk4[rep].w;
      *(float4*)&Vs[j][c4] = vv4[rep];
    }
    __syncthreads();
    // S = Q K^T
    float sacc[4][4] = {};
#pragma unroll 8
    for (int k = 0; k < HDD; ++k) {
      float4 qa = *(const float4*)&Qs[k][ty << 2];
      float4 kb = *(const float4*)&Ks[k][tx << 2];
      float qv[4] = {qa.x, qa.y, qa.z, qa.w};
      float kv[4] = {kb.x, kb.y, kb.z, kb.w};
#pragma unroll
      for (int r = 0; r < 4; ++r)
#pragma unroll
        for (int c = 0; c < 4; ++c)
          sacc[r][c] += qv[r] * kv[c];
    }
    // exp + store transposed + row-sum partials
#pragma unroll
    for (int r = 0; r < 4; ++r) {
      int i = (ty << 2) + r;
      float ls = 0.f;
#pragma unroll
      for (int c = 0; c < 4; ++c) {
        int j = (tx << 2) + c;
        float e = expf(sacc[r][c] * 0.125f + 0.5f * traj[(size_t)(i0 + i) * NN + j0 + j]);
        Ss[j][i] = e;
        ls += e;
      }
      lred[i][tx] = ls;
    }
    __syncthreads();
    if (tid < 64) {
      float s = 0.f;
#pragma unroll
      for (int x = 0; x < 16; ++x) s += lred[tid][x];
      lacc += s;
    }
    // PV
#pragma unroll 8
    for (int j = 0; j < 64; ++j) {
      float4 pa = *(const float4*)&Ss[j][ty << 2];
      float4 vb = *(const float4*)&Vs[j][tx << 2];
      float pv[4] = {pa.x, pa.y, pa.z, pa.w};
      float vv[4] = {vb.x, vb.y, vb.z, vb.w};
#pragma unroll
      for (int r = 0; r < 4; ++r)
#pragma unroll
        for (int c = 0; c < 4; ++c)
          o[r][c] += pv[r] * vv[c];
    }
  }
  if (tid < 64) {
    Lv[(size_t)bh * NN + i0 + tid] = lacc;
    lsc[tid] = 1.f / lacc;
  }
  __syncthreads();
#pragma unroll
  for (int r = 0; r < 4; ++r) {
    int i = (ty << 2) + r;
    float inv = lsc[i];
    float4 ov = make_float4(o[r][0] * inv, o[r][1] * inv, o[r][2] * inv, o[r][3] * inv);
    *(float4*)(AO + ((size_t)(b * NN) + i0 + i) * DD + h * HDD + (tx << 2)) = ov;
  }
}

// ---------------------------------------------------------------------------
// Entropy of head-averaged attention, recomputing scores; certainty update.
__global__ __launch_bounds__(256) void ent_kernel(const float* __restrict__ Q,
                                                  const float* __restrict__ K,
                                                  const float* __restrict__ traj,
                                                  const float* __restrict__ Lv,
                                                  const float* __restrict__ cert,
                                                  float* __restrict__ outc) {
  const int tid = threadIdx.x;
  const int b = blockIdx.y;
  const int i0 = blockIdx.x << 3;  // 8 rows
  __shared__ float Qs[8][1024];
  __shared__ float linv[8][16];
  __shared__ float wred[4][8];
  {
    const float4* Qg = (const float4*)(Q + ((size_t)b * NN + i0) * DD);
    float4* Qs4 = (float4*)&Qs[0][0];
#pragma unroll
    for (int r = 0; r < 8; ++r) Qs4[tid + (r << 8)] = Qg[tid + (r << 8)];
  }
  if (tid < 128) {
    int i = tid >> 4, hh = tid & 15;
    linv[i][hh] = 1.f / Lv[((size_t)(b * NHH + hh)) * NN + i0 + i];
  }
  __syncthreads();
  float Hp[8] = {};
  for (int pt = 0; pt < 2; ++pt) {
    int jA = tid + (pt << 9);
    int jB = jA + 256;
    const float4* KA = (const float4*)(K + ((size_t)b * NN + jA) * DD);
    const float4* KB = (const float4*)(K + ((size_t)b * NN + jB) * DD);
    float trA[8], trB[8];
#pragma unroll
    for (int i = 0; i < 8; ++i) {
      trA[i] = 0.5f * traj[(size_t)(i0 + i) * NN + jA];
      trB[i] = 0.5f * traj[(size_t)(i0 + i) * NN + jB];
    }
    float pbA[8] = {}, pbB[8] = {};
    for (int hh = 0; hh < NHH; ++hh) {
      float aA[8] = {}, aB[8] = {};
#pragma unroll
      for (int kk = 0; kk < 16; ++kk) {
        float4 kA = KA[(hh << 4) + kk];
        float4 kB = KB[(hh << 4) + kk];
#pragma unroll
        for (int i = 0; i < 8; ++i) {
          float4 q = *(const float4*)&Qs[i][(hh << 6) + (kk << 2)];
          aA[i] += q.x * kA.x + q.y * kA.y + q.z * kA.z + q.w * kA.w;
          aB[i] += q.x * kB.x + q.y * kB.y + q.z * kB.z + q.w * kB.w;
        }
      }
#pragma unroll
      for (int i = 0; i < 8; ++i) {
        pbA[i] += expf(aA[i] * 0.125f + trA[i]) * linv[i][hh];
        pbB[i] += expf(aB[i] * 0.125f + trB[i]) * linv[i][hh];
      }
    }
#pragma unroll
    for (int i = 0; i < 8; ++i) {
      float pA = pbA[i] * (1.f / NHH);
      float pB = pbB[i] * (1.f / NHH);
      Hp[i] -= pA * logf(pA) + pB * logf(pB);
    }
  }
#pragma unroll
  for (int i = 0; i < 8; ++i) {
#pragma unroll
    for (int off = 32; off > 0; off >>= 1)
      Hp[i] += __shfl_down(Hp[i], off, 64);
  }
  int lane = tid & 63, wv = tid >> 6;
  if (lane == 0) {
#pragma unroll
    for (int i = 0; i < 8; ++i) wred[wv][i] = Hp[i];
  }
  __syncthreads();
  if (tid < 8) {
    float H = wred[0][tid] + wred[1][tid] + wred[2][tid] + wred[3][tid];
    float sg = 1.f / (1.f + expf(H - HMAXL));
    float c = cert[(size_t)b * NN + i0 + tid];
    outc[(size_t)b * NN + i0 + tid] = fmaxf(c, sg);
  }
}

// ---------------------------------------------------------------------------
extern "C" void kernel_launch(void* const* d_in, const int* in_sizes, int n_in,
                              void* d_out, int out_size, void* d_ws, size_t ws_size,
                              hipStream_t stream) {
  const float* data      = (const float*)d_in[0];
  const float* traj_pos  = (const float*)d_in[1];
  const float* traj_quat = (const float*)d_in[2];
  const float* certainty = (const float*)d_in[3];
  const float* Wq = (const float*)d_in[4];
  const float* bq = (const float*)d_in[5];
  const float* Wk = (const float*)d_in[6];
  const float* bk = (const float*)d_in[7];
  const float* Wv = (const float*)d_in[8];
  const float* bv = (const float*)d_in[9];
  const float* Wo = (const float*)d_in[10];
  const float* bo = (const float*)d_in[11];

  float* ws   = (float*)d_ws;
  float* traj = ws + TRAJ_OFF;
  float* Q    = ws + Q_OFF;
  float* K    = ws + K_OFF;
  float* V    = ws + V_OFF;
  float* AO   = ws + AO_OFF;
  float* Lv   = ws + L_OFF;
  float* out  = (float*)d_out;
  float* outc = out + (size_t)NB * NN * DD;

  traj_kernel<<<NN, 256, 0, stream>>>(traj_pos, traj_quat, traj);
  dim3 ggrid(DD / 64, (NB * NN) / 64);
  gemm_abt_kernel<<<ggrid, 256, 0, stream>>>(data, Wq, bq, Q, NB * NN, DD, DD);
  gemm_abt_kernel<<<ggrid, 256, 0, stream>>>(data, Wk, bk, K, NB * NN, DD, DD);
  gemm_abt_kernel<<<ggrid, 256, 0, stream>>>(data, Wv, bv, V, NB * NN, DD, DD);
  att_kernel<<<dim3(NN / 64, NB * NHH), 256, 0, stream>>>(Q, K, V, traj, AO, Lv);
  ent_kernel<<<dim3(NN / 8, NB), 256, 0, stream>>>(Q, K, traj, Lv, certainty, outc);
  gemm_abt_kernel<<<ggrid, 256, 0, stream>>>(AO, Wo, bo, out, NB * NN, DD, DD);
}

// Round 2
// 633.852 us; speedup vs baseline: 1.2095x; 1.2095x over previous
//
#include <hip/hip_runtime.h>
#include <math.h>

#define NB 2
#define TT 10
#define NN 1024
#define DD 1024
#define NHH 16
#define HDD 64
#define BTT 20   // B*T

// ws offsets in floats
#define TRAJ_OFF 0
#define Q_OFF    1048576            // N*N
#define K_OFF    (Q_OFF + 2097152)  // + B*N*D
#define V_OFF    (K_OFF + 2097152)
#define AO_OFF   (V_OFF + 2097152)
#define L_OFF    (AO_OFF + 2097152) // B*NH*N floats
#define HACC_OFF (L_OFF + 32768)    // B*N floats

#define HMAXL 6.93147180559945f     // log(1024)

// ---------------------------------------------------------------------------
// traj[i,j] = exp(-mean_bt||pi-pj|| - min(mean||qi-qj||, mean||qi+qj||)), row-normalized
__global__ __launch_bounds__(256) void traj_kernel(const float* __restrict__ pos,
                                                   const float* __restrict__ quat,
                                                   float* __restrict__ traj) {
  const int i = blockIdx.x;
  const int tid = threadIdx.x;
  __shared__ float pi[BTT][3];
  __shared__ float qi[BTT][4];
  __shared__ float red[256];
  if (tid < BTT * 3) pi[tid / 3][tid % 3] = pos[((size_t)(tid / 3) * NN + i) * 3 + (tid % 3)];
  if (tid < BTT * 4) qi[tid / 4][tid % 4] = quat[((size_t)(tid / 4) * NN + i) * 4 + (tid % 4)];
  __syncthreads();
  float vj[4];
  float rs = 0.f;
  for (int jt = 0; jt < 4; ++jt) {
    int j = tid + jt * 256;
    float pd = 0.f, qm = 0.f, qp = 0.f;
    for (int bt = 0; bt < BTT; ++bt) {
      const float* pj = pos + ((size_t)bt * NN + j) * 3;
      float dx = pi[bt][0] - pj[0], dy = pi[bt][1] - pj[1], dz = pi[bt][2] - pj[2];
      pd += sqrtf(dx * dx + dy * dy + dz * dz);
      float4 qj = *(const float4*)(quat + ((size_t)bt * NN + j) * 4);
      float a0 = qi[bt][0], a1 = qi[bt][1], a2 = qi[bt][2], a3 = qi[bt][3];
      float m0 = a0 - qj.x, m1 = a1 - qj.y, m2 = a2 - qj.z, m3 = a3 - qj.w;
      float p0 = a0 + qj.x, p1 = a1 + qj.y, p2 = a2 + qj.z, p3 = a3 + qj.w;
      qm += sqrtf(m0 * m0 + m1 * m1 + m2 * m2 + m3 * m3);
      qp += sqrtf(p0 * p0 + p1 * p1 + p2 * p2 + p3 * p3);
    }
    float v = expf(-(pd + fminf(qm, qp)) * (1.f / BTT));
    vj[jt] = v;
    rs += v;
  }
  red[tid] = rs;
  __syncthreads();
  for (int s = 128; s > 0; s >>= 1) {
    if (tid < s) red[tid] += red[tid + s];
    __syncthreads();
  }
  float inv = 1.f / red[0];
  for (int jt = 0; jt < 4; ++jt)
    traj[(size_t)i * NN + tid + jt * 256] = vj[jt] * inv;
}

// ---------------------------------------------------------------------------
// C[M,Nc] = A[M,Kc] @ W[Nc,Kc]^T + bias   (all dims multiples of 64)
__global__ __launch_bounds__(256) void gemm_abt_kernel(const float* __restrict__ A,
                                                       const float* __restrict__ W,
                                                       const float* __restrict__ bias,
                                                       float* __restrict__ C,
                                                       int M, int Nc, int Kc) {
  __shared__ float As[16][68];  // [k][m]
  __shared__ float Ws[16][68];  // [k][n]
  const int tid = threadIdx.x;
  const int bm = blockIdx.y << 6, bn = blockIdx.x << 6;
  const int tx = tid & 15, ty = tid >> 4;
  const int lr = tid >> 2, lk = (tid & 3) << 2;
  float acc[4][4] = {};
  for (int k0 = 0; k0 < Kc; k0 += 16) {
    float4 a4 = *(const float4*)(A + (size_t)(bm + lr) * Kc + k0 + lk);
    float4 w4 = *(const float4*)(W + (size_t)(bn + lr) * Kc + k0 + lk);
    __syncthreads();
    As[lk + 0][lr] = a4.x; As[lk + 1][lr] = a4.y; As[lk + 2][lr] = a4.z; As[lk + 3][lr] = a4.w;
    Ws[lk + 0][lr] = w4.x; Ws[lk + 1][lr] = w4.y; Ws[lk + 2][lr] = w4.z; Ws[lk + 3][lr] = w4.w;
    __syncthreads();
#pragma unroll
    for (int k = 0; k < 16; ++k) {
      float4 av = *(const float4*)&As[k][ty << 2];
      float4 wv = *(const float4*)&Ws[k][tx << 2];
      float avv[4] = {av.x, av.y, av.z, av.w};
      float wvv[4] = {wv.x, wv.y, wv.z, wv.w};
#pragma unroll
      for (int r = 0; r < 4; ++r)
#pragma unroll
        for (int c = 0; c < 4; ++c)
          acc[r][c] += avv[r] * wvv[c];
    }
  }
  float4 b4 = *(const float4*)(bias + bn + (tx << 2));
  float bb[4] = {b4.x, b4.y, b4.z, b4.w};
#pragma unroll
  for (int r = 0; r < 4; ++r) {
    float4 ov = make_float4(acc[r][0] + bb[0], acc[r][1] + bb[1],
                            acc[r][2] + bb[2], acc[r][3] + bb[3]);
    *(float4*)(C + (size_t)(bm + (ty << 2) + r) * Nc + bn + (tx << 2)) = ov;
  }
}

// ---------------------------------------------------------------------------
// Fused attention per (b,h): AO[b,i,h*64+d] = softmax(QK^T/8 + 0.5*traj) @ V
// Also stores softmax denominators Lv[(b*NH+h)*N + i] (no-max softmax; scores bounded ~|6|).
__global__ __launch_bounds__(256) void att_kernel(const float* __restrict__ Q,
                                                  const float* __restrict__ K,
                                                  const float* __restrict__ V,
                                                  const float* __restrict__ traj,
                                                  float* __restrict__ AO,
                                                  float* __restrict__ Lv) {
  const int tid = threadIdx.x;
  const int bh = blockIdx.y;
  const int b = bh >> 4, h = bh & 15;
  const int i0 = blockIdx.x << 6;
  const int tx = tid & 15, ty = tid >> 4;
  __shared__ float Qs[HDD][68];  // [k][i]
  __shared__ float Ks[HDD][68];  // [k][j]
  __shared__ float Vs[64][68];   // [j][d]
  __shared__ float Ss[64][68];   // [j][i]  (exp'd scores)
  __shared__ float lred[64][17];
  __shared__ float lsc[64];
  const int r0 = tid >> 4;
  const int c4 = (tid & 15) << 2;
  // stage Q tile transposed
#pragma unroll
  for (int rep = 0; rep < 4; ++rep) {
    int i = r0 + (rep << 4);
    float4 q4 = *(const float4*)(Q + ((size_t)(b * NN) + i0 + i) * DD + h * HDD + c4);
    Qs[c4 + 0][i] = q4.x; Qs[c4 + 1][i] = q4.y; Qs[c4 + 2][i] = q4.z; Qs[c4 + 3][i] = q4.w;
  }
  float o[4][4] = {};
  float lacc = 0.f;  // owner threads (tid<64) accumulate l for i=tid
  for (int j0 = 0; j0 < NN; j0 += 64) {
    float4 kk4[4], vv4[4];
#pragma unroll
    for (int rep = 0; rep < 4; ++rep) {
      int j = r0 + (rep << 4);
      kk4[rep] = *(const float4*)(K + ((size_t)(b * NN) + j0 + j) * DD + h * HDD + c4);
      vv4[rep] = *(const float4*)(V + ((size_t)(b * NN) + j0 + j) * DD + h * HDD + c4);
    }
    __syncthreads();  // previous iter's PV / S reads done
#pragma unroll
    for (int rep = 0; rep < 4; ++rep) {
      int j = r0 + (rep << 4);
      Ks[c4 + 0][j] = kk4[rep].x; Ks[c4 + 1][j] = kk4[rep].y;
      Ks[c4 + 2][j] = kk4[rep].z; Ks[c4 + 3][j] = kk4[rep].w;
      *(float4*)&Vs[j][c4] = vv4[rep];
    }
    __syncthreads();
    // S = Q K^T
    float sacc[4][4] = {};
#pragma unroll 8
    for (int k = 0; k < HDD; ++k) {
      float4 qa = *(const float4*)&Qs[k][ty << 2];
      float4 kb = *(const float4*)&Ks[k][tx << 2];
      float qv[4] = {qa.x, qa.y, qa.z, qa.w};
      float kv[4] = {kb.x, kb.y, kb.z, kb.w};
#pragma unroll
      for (int r = 0; r < 4; ++r)
#pragma unroll
        for (int c = 0; c < 4; ++c)
          sacc[r][c] += qv[r] * kv[c];
    }
    // exp + store transposed + row-sum partials
#pragma unroll
    for (int r = 0; r < 4; ++r) {
      int i = (ty << 2) + r;
      float ls = 0.f;
#pragma unroll
      for (int c = 0; c < 4; ++c) {
        int j = (tx << 2) + c;
        float e = expf(sacc[r][c] * 0.125f + 0.5f * traj[(size_t)(i0 + i) * NN + j0 + j]);
        Ss[j][i] = e;
        ls += e;
      }
      lred[i][tx] = ls;
    }
    __syncthreads();
    if (tid < 64) {
      float s = 0.f;
#pragma unroll
      for (int x = 0; x < 16; ++x) s += lred[tid][x];
      lacc += s;
    }
    // PV
#pragma unroll 8
    for (int j = 0; j < 64; ++j) {
      float4 pa = *(const float4*)&Ss[j][ty << 2];
      float4 vb = *(const float4*)&Vs[j][tx << 2];
      float pv[4] = {pa.x, pa.y, pa.z, pa.w};
      float vv[4] = {vb.x, vb.y, vb.z, vb.w};
#pragma unroll
      for (int r = 0; r < 4; ++r)
#pragma unroll
        for (int c = 0; c < 4; ++c)
          o[r][c] += pv[r] * vv[c];
    }
  }
  if (tid < 64) {
    Lv[(size_t)bh * NN + i0 + tid] = lacc;
    lsc[tid] = 1.f / lacc;
  }
  __syncthreads();
#pragma unroll
  for (int r = 0; r < 4; ++r) {
    int i = (ty << 2) + r;
    float inv = lsc[i];
    float4 ov = make_float4(o[r][0] * inv, o[r][1] * inv, o[r][2] * inv, o[r][3] * inv);
    *(float4*)(AO + ((size_t)(b * NN) + i0 + i) * DD + h * HDD + (tx << 2)) = ov;
  }
}

// ---------------------------------------------------------------------------
// Entropy, restructured as tiled GEMM + epilogue.
// Grid (j-tiles=16, i-tiles=16, b=2) = 512 blocks. Each block computes the
// 64x64 score tile for all 16 heads (64-wide k-slabs in LDS), accumulates
// p = sum_h e/l, then reduces -p log p over its j-range and atomicAdds into
// Hacc[b*N + i].
__global__ __launch_bounds__(256) void ent2_kernel(const float* __restrict__ Q,
                                                   const float* __restrict__ K,
                                                   const float* __restrict__ traj,
                                                   const float* __restrict__ Lv,
                                                   float* __restrict__ Hacc) {
  const int tid = threadIdx.x;
  const int j0 = blockIdx.x << 6;
  const int i0 = blockIdx.y << 6;
  const int b  = blockIdx.z;
  const int tx = tid & 15, ty = tid >> 4;
  __shared__ float Qs[64][68];   // [k][i]
  __shared__ float Ks[64][68];   // [k][j]
  __shared__ float ts[64][68];   // [i][j] 0.5*traj
  __shared__ float linv[NHH][64];
  __shared__ float lred[64][17];
  // load 1/l for the 16 heads x 64 rows
#pragma unroll
  for (int rep = 0; rep < 4; ++rep) {
    int idx = tid + (rep << 8);
    int h = idx >> 6, i = idx & 63;
    linv[h][i] = 1.f / Lv[((size_t)((b << 4) + h)) * NN + i0 + i];
  }
  // load traj tile scaled by 0.5
#pragma unroll
  for (int rep = 0; rep < 4; ++rep) {
    int lin = tid + (rep << 8);          // float4 index within 64x64 tile
    int row = lin >> 4, cc = (lin & 15) << 2;
    float4 t4 = *(const float4*)(traj + (size_t)(i0 + row) * NN + j0 + cc);
    ts[row][cc + 0] = 0.5f * t4.x; ts[row][cc + 1] = 0.5f * t4.y;
    ts[row][cc + 2] = 0.5f * t4.z; ts[row][cc + 3] = 0.5f * t4.w;
  }
  const int lr = tid >> 2;             // 0..63: row within tile
  const int ls = (tid & 3) << 2;       // col slot base (stride 16 per rep)
  float P[4][4] = {};
  for (int h = 0; h < NHH; ++h) {
    float4 qreg[4], kreg[4];
#pragma unroll
    for (int rep = 0; rep < 4; ++rep) {
      int col = ls + (rep << 4);
      qreg[rep] = *(const float4*)(Q + ((size_t)(b * NN) + i0 + lr) * DD + (h << 6) + col);
      kreg[rep] = *(const float4*)(K + ((size_t)(b * NN) + j0 + lr) * DD + (h << 6) + col);
    }
    __syncthreads();  // prior inner-loop reads (and, at h=0, ts/linv writes) done
#pragma unroll
    for (int rep = 0; rep < 4; ++rep) {
      int col = ls + (rep << 4);
      Qs[col + 0][lr] = qreg[rep].x; Qs[col + 1][lr] = qreg[rep].y;
      Qs[col + 2][lr] = qreg[rep].z; Qs[col + 3][lr] = qreg[rep].w;
      Ks[col + 0][lr] = kreg[rep].x; Ks[col + 1][lr] = kreg[rep].y;
      Ks[col + 2][lr] = kreg[rep].z; Ks[col + 3][lr] = kreg[rep].w;
    }
    __syncthreads();
    float acc[4][4] = {};
#pragma unroll 8
    for (int k = 0; k < HDD; ++k) {
      float4 qa = *(const float4*)&Qs[k][ty << 2];
      float4 kb = *(const float4*)&Ks[k][tx << 2];
      float qv[4] = {qa.x, qa.y, qa.z, qa.w};
      float kv[4] = {kb.x, kb.y, kb.z, kb.w};
#pragma unroll
      for (int r = 0; r < 4; ++r)
#pragma unroll
        for (int c = 0; c < 4; ++c)
          acc[r][c] += qv[r] * kv[c];
    }
#pragma unroll
    for (int r = 0; r < 4; ++r) {
      int i = (ty << 2) + r;
      float li = linv[h][i];
      float4 t4 = *(const float4*)&ts[i][tx << 2];
      float tv[4] = {t4.x, t4.y, t4.z, t4.w};
#pragma unroll
      for (int c = 0; c < 4; ++c)
        P[r][c] += expf(acc[r][c] * 0.125f + tv[c]) * li;
    }
  }
  // entropy partials: p = P/16, hs = -sum p log p over this thread's 4 j's
#pragma unroll
  for (int r = 0; r < 4; ++r) {
    float hs = 0.f;
#pragma unroll
    for (int c = 0; c < 4; ++c) {
      float p = P[r][c] * (1.f / NHH);
      hs -= p * logf(p);
    }
    lred[(ty << 2) + r][tx] = hs;
  }
  __syncthreads();
  if (tid < 64) {
    float s = 0.f;
#pragma unroll
    for (int x = 0; x < 16; ++x) s += lred[tid][x];
    atomicAdd(&Hacc[(size_t)b * NN + i0 + tid], s);
  }
}

__global__ __launch_bounds__(256) void zero_hacc_kernel(float* __restrict__ Hacc) {
  Hacc[blockIdx.x * 256 + threadIdx.x] = 0.f;
}

__global__ __launch_bounds__(256) void cert_kernel(const float* __restrict__ Hacc,
                                                   const float* __restrict__ cert,
                                                   float* __restrict__ outc) {
  int idx = blockIdx.x * 256 + threadIdx.x;
  float H = Hacc[idx];
  float sg = 1.f / (1.f + expf(H - HMAXL));
  outc[idx] = fmaxf(cert[idx], sg);
}

// ---------------------------------------------------------------------------
extern "C" void kernel_launch(void* const* d_in, const int* in_sizes, int n_in,
                              void* d_out, int out_size, void* d_ws, size_t ws_size,
                              hipStream_t stream) {
  const float* data      = (const float*)d_in[0];
  const float* traj_pos  = (const float*)d_in[1];
  const float* traj_quat = (const float*)d_in[2];
  const float* certainty = (const float*)d_in[3];
  const float* Wq = (const float*)d_in[4];
  const float* bq = (const float*)d_in[5];
  const float* Wk = (const float*)d_in[6];
  const float* bk = (const float*)d_in[7];
  const float* Wv = (const float*)d_in[8];
  const float* bv = (const float*)d_in[9];
  const float* Wo = (const float*)d_in[10];
  const float* bo = (const float*)d_in[11];

  float* ws   = (float*)d_ws;
  float* traj = ws + TRAJ_OFF;
  float* Q    = ws + Q_OFF;
  float* K    = ws + K_OFF;
  float* V    = ws + V_OFF;
  float* AO   = ws + AO_OFF;
  float* Lv   = ws + L_OFF;
  float* Hacc = ws + HACC_OFF;
  float* out  = (float*)d_out;
  float* outc = out + (size_t)NB * NN * DD;

  traj_kernel<<<NN, 256, 0, stream>>>(traj_pos, traj_quat, traj);
  zero_hacc_kernel<<<(NB * NN) / 256, 256, 0, stream>>>(Hacc);
  dim3 ggrid(DD / 64, (NB * NN) / 64);
  gemm_abt_kernel<<<ggrid, 256, 0, stream>>>(data, Wq, bq, Q, NB * NN, DD, DD);
  gemm_abt_kernel<<<ggrid, 256, 0, stream>>>(data, Wk, bk, K, NB * NN, DD, DD);
  gemm_abt_kernel<<<ggrid, 256, 0, stream>>>(data, Wv, bv, V, NB * NN, DD, DD);
  att_kernel<<<dim3(NN / 64, NB * NHH), 256, 0, stream>>>(Q, K, V, traj, AO, Lv);
  ent2_kernel<<<dim3(NN / 64, NN / 64, NB), 256, 0, stream>>>(Q, K, traj, Lv, Hacc);
  cert_kernel<<<(NB * NN) / 256, 256, 0, stream>>>(Hacc, certainty, outc);
  gemm_abt_kernel<<<ggrid, 256, 0, stream>>>(AO, Wo, bo, out, NB * NN, DD, DD);
}

// Round 3
// 241.999 us; speedup vs baseline: 3.1681x; 2.6192x over previous
//
#include <hip/hip_runtime.h>
#include <math.h>

#define NB 2
#define NN 1024
#define DD 1024
#define NHH 16
#define HDD 64
#define BTT 20

typedef unsigned short u16;
typedef short bf16x8 __attribute__((ext_vector_type(8)));
typedef float f32x4 __attribute__((ext_vector_type(4)));

#define HMAXL 6.93147180559945f
#define C1 0.18033688011112042f   // 0.125 * log2(e)
#define TLC 0.72134752044448170f  // 0.5 * log2(e)

// ws offsets in floats
#define TRAJ_OFF 0
#define TL_OFF    1048576   // N*N bf16 -> 524288 float slots
#define DATAB_OFF 1572864   // 2M bf16 -> 1048576
#define WQB_OFF   2621440   // 1M bf16 -> 524288
#define WKB_OFF   3145728
#define WVB_OFF   3670016
#define WOB_OFF   4194304
#define QB_OFF    4718592   // 2M bf16
#define KB_OFF    5767168
#define VT_OFF    6815744
#define AOB_OFF   7864320
#define LV_OFF    8912896   // 32768 f
#define HACC_OFF  8945664   // 2048 f

__device__ __forceinline__ float b2f(u16 h) { return __uint_as_float(((unsigned)h) << 16); }
__device__ __forceinline__ u16 f2bf(float f) {
  unsigned u = __float_as_uint(f);
  return (u16)((u + 0x7fffu + ((u >> 16) & 1u)) >> 16);
}
__device__ __forceinline__ void dma16(const void* g, void* l) {
  __builtin_amdgcn_global_load_lds((const __attribute__((address_space(1))) void*)g,
                                   (__attribute__((address_space(3))) void*)l, 16, 0, 0);
}

// ---------------------------------------------------------------------------
__global__ __launch_bounds__(256) void conv_data_kernel(const float* __restrict__ src,
                                                        u16* __restrict__ dst) {
  int i = (blockIdx.x * 256 + threadIdx.x) * 4;
  float4 v = *(const float4*)(src + i);
  ushort4 o = {f2bf(v.x), f2bf(v.y), f2bf(v.z), f2bf(v.w)};
  *(ushort4*)(dst + i) = o;
}

__global__ __launch_bounds__(256) void conv_w_kernel(const float* __restrict__ w0,
                                                     const float* __restrict__ w1,
                                                     const float* __restrict__ w2,
                                                     const float* __restrict__ w3,
                                                     u16* __restrict__ d0, u16* __restrict__ d1,
                                                     u16* __restrict__ d2, u16* __restrict__ d3) {
  int z = blockIdx.y;
  const float* s = z == 0 ? w0 : (z == 1 ? w1 : (z == 2 ? w2 : w3));
  u16* d = z == 0 ? d0 : (z == 1 ? d1 : (z == 2 ? d2 : d3));
  int i = (blockIdx.x * 256 + threadIdx.x) * 4;
  float4 v = *(const float4*)(s + i);
  ushort4 o = {f2bf(v.x), f2bf(v.y), f2bf(v.z), f2bf(v.w)};
  *(ushort4*)(d + i) = o;
}

// ---------------------------------------------------------------------------
__global__ __launch_bounds__(256) void traj_kernel(const float* __restrict__ pos,
                                                   const float* __restrict__ quat,
                                                   float* __restrict__ traj,
                                                   u16* __restrict__ tl) {
  const int i = blockIdx.x;
  const int tid = threadIdx.x;
  __shared__ float pi[BTT][3];
  __shared__ float qi[BTT][4];
  __shared__ float red[256];
  if (tid < BTT * 3) pi[tid / 3][tid % 3] = pos[((size_t)(tid / 3) * NN + i) * 3 + (tid % 3)];
  if (tid < BTT * 4) qi[tid / 4][tid % 4] = quat[((size_t)(tid / 4) * NN + i) * 4 + (tid % 4)];
  __syncthreads();
  float vj[4];
  float rs = 0.f;
  for (int jt = 0; jt < 4; ++jt) {
    int j = tid + jt * 256;
    float pd = 0.f, qm = 0.f, qp = 0.f;
    for (int bt = 0; bt < BTT; ++bt) {
      const float* pj = pos + ((size_t)bt * NN + j) * 3;
      float dx = pi[bt][0] - pj[0], dy = pi[bt][1] - pj[1], dz = pi[bt][2] - pj[2];
      pd += sqrtf(dx * dx + dy * dy + dz * dz);
      float4 qj = *(const float4*)(quat + ((size_t)bt * NN + j) * 4);
      float a0 = qi[bt][0], a1 = qi[bt][1], a2 = qi[bt][2], a3 = qi[bt][3];
      float m0 = a0 - qj.x, m1 = a1 - qj.y, m2 = a2 - qj.z, m3 = a3 - qj.w;
      float p0 = a0 + qj.x, p1 = a1 + qj.y, p2 = a2 + qj.z, p3 = a3 + qj.w;
      qm += sqrtf(m0 * m0 + m1 * m1 + m2 * m2 + m3 * m3);
      qp += sqrtf(p0 * p0 + p1 * p1 + p2 * p2 + p3 * p3);
    }
    float v = expf(-(pd + fminf(qm, qp)) * (1.f / BTT));
    vj[jt] = v;
    rs += v;
  }
  red[tid] = rs;
  __syncthreads();
  for (int s = 128; s > 0; s >>= 1) {
    if (tid < s) red[tid] += red[tid + s];
    __syncthreads();
  }
  float inv = 1.f / red[0];
  for (int jt = 0; jt < 4; ++jt) {
    int j = tid + jt * 256;
    float t = vj[jt] * inv;
    traj[(size_t)i * NN + j] = t;
    tl[(size_t)i * NN + j] = f2bf(t * TLC);
  }
}

// ---------------------------------------------------------------------------
// Fused QKV projection GEMM, bf16 MFMA. C[M=2048][N=1024] = A @ W^T + bias.
// BM=128, BN=64, BK=32. 4 waves, wave-tile 64x32. z selects Q/K/V.
// z==2 (V) writes output transposed into Vt[(b*16+h)*64+d][tok].
__global__ __launch_bounds__(256) void gemm_qkv_kernel(const u16* __restrict__ Ab,
                                                       const u16* __restrict__ Wq,
                                                       const u16* __restrict__ Wk,
                                                       const u16* __restrict__ Wv,
                                                       const float* __restrict__ bq,
                                                       const float* __restrict__ bk,
                                                       const float* __restrict__ bv,
                                                       u16* __restrict__ Qb,
                                                       u16* __restrict__ Kb,
                                                       u16* __restrict__ VtT) {
  const int z = blockIdx.z;
  const u16* Wb = z == 0 ? Wq : (z == 1 ? Wk : Wv);
  const float* bias = z == 0 ? bq : (z == 1 ? bk : bv);
  __shared__ __align__(16) u16 As[128 * 32];
  __shared__ __align__(16) u16 Ws[64 * 32];
  const int tid = threadIdx.x;
  const int w = tid >> 6, l = tid & 63, g = l >> 4, ln = l & 15;
  const int bm = blockIdx.y << 7, bn = blockIdx.x << 6;
  const int rowA0 = w * 32 + (l >> 2), rowA1 = rowA0 + 16;
  const int colA = (l & 3) * 8;
  const int rowB = w * 16 + (l >> 2);
  const u16* Aptr0 = Ab + (size_t)(bm + rowA0) * DD + colA;
  const u16* Aptr1 = Ab + (size_t)(bm + rowA1) * DD + colA;
  const u16* Bptr = Wb + (size_t)(bn + rowB) * DD + colA;
  u16* ldsA0 = As + (w * 2) * 512;
  u16* ldsA1 = As + (w * 2 + 1) * 512;
  u16* ldsB = Ws + w * 512;
  f32x4 zero4 = {0.f, 0.f, 0.f, 0.f};
  f32x4 acc[4][2];
#pragma unroll
  for (int mt = 0; mt < 4; ++mt) { acc[mt][0] = zero4; acc[mt][1] = zero4; }
  const int mlo = (w & 1) * 64, nlo = (w >> 1) * 32;
  for (int k0 = 0; k0 < DD; k0 += 32) {
    __syncthreads();
    dma16(Aptr0 + k0, ldsA0);
    dma16(Aptr1 + k0, ldsA1);
    dma16(Bptr + k0, ldsB);
    __syncthreads();
    bf16x8 bfr[2];
#pragma unroll
    for (int nt = 0; nt < 2; ++nt)
      bfr[nt] = *(const bf16x8*)&Ws[(nlo + nt * 16 + ln) * 32 + g * 8];
#pragma unroll
    for (int mt = 0; mt < 4; ++mt) {
      bf16x8 af = *(const bf16x8*)&As[(mlo + mt * 16 + ln) * 32 + g * 8];
#pragma unroll
      for (int nt = 0; nt < 2; ++nt)
        acc[mt][nt] = __builtin_amdgcn_mfma_f32_16x16x32_bf16(af, bfr[nt], acc[mt][nt], 0, 0, 0);
    }
  }
  // epilogue
#pragma unroll
  for (int nt = 0; nt < 2; ++nt) {
    int n = bn + nlo + nt * 16 + ln;
    float bb = bias[n];
    if (z == 2) {
      int row = (((bm >> 10) << 4) + (n >> 6)) * 64 + (n & 63);
#pragma unroll
      for (int mt = 0; mt < 4; ++mt) {
        int tok = ((bm & 1023) + mlo + mt * 16 + g * 4);
        ushort4 pk = {f2bf(acc[mt][nt][0] + bb), f2bf(acc[mt][nt][1] + bb),
                      f2bf(acc[mt][nt][2] + bb), f2bf(acc[mt][nt][3] + bb)};
        *(ushort4*)(VtT + (size_t)row * NN + tok) = pk;
      }
    } else {
      u16* outp = z == 0 ? Qb : Kb;
#pragma unroll
      for (int mt = 0; mt < 4; ++mt) {
#pragma unroll
        for (int r = 0; r < 4; ++r) {
          int m = bm + mlo + mt * 16 + g * 4 + r;
          outp[(size_t)m * DD + n] = f2bf(acc[mt][nt][r] + bb);
        }
      }
    }
  }
}

// ---------------------------------------------------------------------------
// Output projection GEMM: out[M][N] fp32 = AOb @ Wo^T + bo.
__global__ __launch_bounds__(256) void gemm_o_kernel(const u16* __restrict__ Ab,
                                                     const u16* __restrict__ Wb,
                                                     const float* __restrict__ bias,
                                                     float* __restrict__ C) {
  __shared__ __align__(16) u16 As[128 * 32];
  __shared__ __align__(16) u16 Ws[64 * 32];
  const int tid = threadIdx.x;
  const int w = tid >> 6, l = tid & 63, g = l >> 4, ln = l & 15;
  const int bm = blockIdx.y << 7, bn = blockIdx.x << 6;
  const int rowA0 = w * 32 + (l >> 2), rowA1 = rowA0 + 16;
  const int colA = (l & 3) * 8;
  const int rowB = w * 16 + (l >> 2);
  const u16* Aptr0 = Ab + (size_t)(bm + rowA0) * DD + colA;
  const u16* Aptr1 = Ab + (size_t)(bm + rowA1) * DD + colA;
  const u16* Bptr = Wb + (size_t)(bn + rowB) * DD + colA;
  u16* ldsA0 = As + (w * 2) * 512;
  u16* ldsA1 = As + (w * 2 + 1) * 512;
  u16* ldsB = Ws + w * 512;
  f32x4 zero4 = {0.f, 0.f, 0.f, 0.f};
  f32x4 acc[4][2];
#pragma unroll
  for (int mt = 0; mt < 4; ++mt) { acc[mt][0] = zero4; acc[mt][1] = zero4; }
  const int mlo = (w & 1) * 64, nlo = (w >> 1) * 32;
  for (int k0 = 0; k0 < DD; k0 += 32) {
    __syncthreads();
    dma16(Aptr0 + k0, ldsA0);
    dma16(Aptr1 + k0, ldsA1);
    dma16(Bptr + k0, ldsB);
    __syncthreads();
    bf16x8 bfr[2];
#pragma unroll
    for (int nt = 0; nt < 2; ++nt)
      bfr[nt] = *(const bf16x8*)&Ws[(nlo + nt * 16 + ln) * 32 + g * 8];
#pragma unroll
    for (int mt = 0; mt < 4; ++mt) {
      bf16x8 af = *(const bf16x8*)&As[(mlo + mt * 16 + ln) * 32 + g * 8];
#pragma unroll
      for (int nt = 0; nt < 2; ++nt)
        acc[mt][nt] = __builtin_amdgcn_mfma_f32_16x16x32_bf16(af, bfr[nt], acc[mt][nt], 0, 0, 0);
    }
  }
#pragma unroll
  for (int nt = 0; nt < 2; ++nt) {
    int n = bn + nlo + nt * 16 + ln;
    float bb = bias[n];
#pragma unroll
    for (int mt = 0; mt < 4; ++mt) {
#pragma unroll
      for (int r = 0; r < 4; ++r) {
        int m = bm + mlo + mt * 16 + g * 4 + r;
        C[(size_t)m * DD + n] = acc[mt][nt][r] + bb;
      }
    }
  }
}

// ---------------------------------------------------------------------------
// MFMA flash attention per (b,h,i-tile 64). Computes S^T = K Q^T so P packs
// j-contiguously; PV uses Vt (transposed V). No-max softmax (scores ~|6|).
__global__ __launch_bounds__(256) void att_kernel(const u16* __restrict__ Qb,
                                                  const u16* __restrict__ Kb,
                                                  const u16* __restrict__ VtT,
                                                  const u16* __restrict__ tl,
                                                  u16* __restrict__ AOb,
                                                  float* __restrict__ Lv) {
  const int tid = threadIdx.x;
  const int bh = blockIdx.y;
  const int b = bh >> 4, h = bh & 15;
  const int i0 = blockIdx.x << 6;
  const int w = tid >> 6, l = tid & 63, g = l >> 4, ln = l & 15;
  const int wi0 = w * 16;
  __shared__ __align__(16) u16 Qs[64 * 64];
  __shared__ __align__(16) u16 Ks[64 * 64];
  __shared__ __align__(16) u16 Vts[64 * 64];
  __shared__ __align__(16) u16 Pt[64 * 72];
  __shared__ float lsc[64];
  // DMA rows: q = w*2+t, row = q*8 + l/8, col = (l%8)*8
  const int drow0 = w * 16 + (l >> 3), drow1 = drow0 + 8;
  const int dcol = (l & 7) * 8;
  // Q tile (once)
  dma16(Qb + ((size_t)(b * NN) + i0 + drow0) * DD + h * HDD + dcol, Qs + (w * 2) * 512);
  dma16(Qb + ((size_t)(b * NN) + i0 + drow1) * DD + h * HDD + dcol, Qs + (w * 2 + 1) * 512);
  const int ig = i0 + wi0 + ln;  // this lane's global i (col of S^T)
  f32x4 zero4 = {0.f, 0.f, 0.f, 0.f};
  f32x4 oacc[4];
#pragma unroll
  for (int nt = 0; nt < 4; ++nt) oacc[nt] = zero4;
  float lacc = 0.f;
  for (int j0 = 0; j0 < NN; j0 += 64) {
    __syncthreads();  // prior step's LDS reads done (also drains Q DMA at j0=0)
    dma16(Kb + ((size_t)(b * NN) + j0 + drow0) * DD + h * HDD + dcol, Ks + (w * 2) * 512);
    dma16(Kb + ((size_t)(b * NN) + j0 + drow1) * DD + h * HDD + dcol, Ks + (w * 2 + 1) * 512);
    dma16(VtT + ((size_t)(bh * 64) + drow0) * NN + j0 + dcol, Vts + (w * 2) * 512);
    dma16(VtT + ((size_t)(bh * 64) + drow1) * NN + j0 + dcol, Vts + (w * 2 + 1) * 512);
    ushort4 tlv[4];
#pragma unroll
    for (int jt = 0; jt < 4; ++jt)
      tlv[jt] = *(const ushort4*)(tl + (size_t)ig * NN + j0 + jt * 16 + g * 4);
    __syncthreads();  // DMAs complete
    bf16x8 qf[2];
    qf[0] = *(const bf16x8*)&Qs[(wi0 + ln) * 64 + g * 8];
    qf[1] = *(const bf16x8*)&Qs[(wi0 + ln) * 64 + 32 + g * 8];
    f32x4 sacc[4];
#pragma unroll
    for (int jt = 0; jt < 4; ++jt) {
      sacc[jt] = zero4;
#pragma unroll
      for (int kc = 0; kc < 2; ++kc) {
        bf16x8 af = *(const bf16x8*)&Ks[(jt * 16 + ln) * 64 + kc * 32 + g * 8];
        sacc[jt] = __builtin_amdgcn_mfma_f32_16x16x32_bf16(af, qf[kc], sacc[jt], 0, 0, 0);
      }
    }
    // exp + pack to Pt + l partial
#pragma unroll
    for (int jt = 0; jt < 4; ++jt) {
      float e0 = exp2f(sacc[jt][0] * C1 + b2f(tlv[jt].x));
      float e1 = exp2f(sacc[jt][1] * C1 + b2f(tlv[jt].y));
      float e2 = exp2f(sacc[jt][2] * C1 + b2f(tlv[jt].z));
      float e3 = exp2f(sacc[jt][3] * C1 + b2f(tlv[jt].w));
      lacc += (e0 + e1) + (e2 + e3);
      ushort4 pk = {f2bf(e0), f2bf(e1), f2bf(e2), f2bf(e3)};
      *(ushort4*)(Pt + (wi0 + ln) * 72 + jt * 16 + g * 4) = pk;
    }
    __syncthreads();  // Pt visible
    bf16x8 pf[2];
    pf[0] = *(const bf16x8*)&Pt[(wi0 + ln) * 72 + g * 8];
    pf[1] = *(const bf16x8*)&Pt[(wi0 + ln) * 72 + 32 + g * 8];
#pragma unroll
    for (int nt = 0; nt < 4; ++nt) {
#pragma unroll
      for (int kc = 0; kc < 2; ++kc) {
        bf16x8 vf = *(const bf16x8*)&Vts[(nt * 16 + ln) * 64 + kc * 32 + g * 8];
        oacc[nt] = __builtin_amdgcn_mfma_f32_16x16x32_bf16(pf[kc], vf, oacc[nt], 0, 0, 0);
      }
    }
  }
  // total l for i = ig: combine the 4 g-groups
  lacc += __shfl_xor(lacc, 16, 64);
  lacc += __shfl_xor(lacc, 32, 64);
  if (g == 0) {
    Lv[(size_t)bh * NN + i0 + wi0 + ln] = lacc;
    lsc[wi0 + ln] = 1.f / lacc;
  }
  __syncthreads();
#pragma unroll
  for (int nt = 0; nt < 4; ++nt) {
    int d = nt * 16 + ln;
#pragma unroll
    for (int r = 0; r < 4; ++r) {
      int i = wi0 + g * 4 + r;
      float v = oacc[nt][r] * lsc[i];
      AOb[((size_t)(b * NN) + i0 + i) * DD + h * HDD + d] = f2bf(v);
    }
  }
}

// ---------------------------------------------------------------------------
// Entropy via MFMA: per (j-tile, i-tile, b) block, loop heads, accumulate
// p = sum_h e/l_h, epilogue -p log p reduced over j, atomicAdd into Hacc.
__global__ __launch_bounds__(256) void ent_kernel(const u16* __restrict__ Qb,
                                                  const u16* __restrict__ Kb,
                                                  const u16* __restrict__ tl,
                                                  const float* __restrict__ Lv,
                                                  float* __restrict__ Hacc) {
  const int tid = threadIdx.x;
  const int j0 = blockIdx.x << 6;
  const int i0 = blockIdx.y << 6;
  const int b = blockIdx.z;
  const int w = tid >> 6, l = tid & 63, g = l >> 4, ln = l & 15;
  const int wi0 = w * 16;
  __shared__ __align__(16) u16 Qs[64 * 64];
  __shared__ __align__(16) u16 Ks[64 * 64];
  __shared__ float linv[NHH][64];
#pragma unroll
  for (int rep = 0; rep < 4; ++rep) {
    int idx = tid + (rep << 8);
    int hh = idx >> 6, ii = idx & 63;
    linv[hh][ii] = 1.f / Lv[((size_t)((b << 4) + hh)) * NN + i0 + ii];
  }
  const int drow0 = w * 16 + (l >> 3), drow1 = drow0 + 8;
  const int dcol = (l & 7) * 8;
  const int ig = i0 + wi0 + ln;
  ushort4 tlv[4];
#pragma unroll
  for (int jt = 0; jt < 4; ++jt)
    tlv[jt] = *(const ushort4*)(tl + (size_t)ig * NN + j0 + jt * 16 + g * 4);
  float P[4][4] = {};
  f32x4 zero4 = {0.f, 0.f, 0.f, 0.f};
  for (int h = 0; h < NHH; ++h) {
    __syncthreads();
    dma16(Qb + ((size_t)(b * NN) + i0 + drow0) * DD + h * HDD + dcol, Qs + (w * 2) * 512);
    dma16(Qb + ((size_t)(b * NN) + i0 + drow1) * DD + h * HDD + dcol, Qs + (w * 2 + 1) * 512);
    dma16(Kb + ((size_t)(b * NN) + j0 + drow0) * DD + h * HDD + dcol, Ks + (w * 2) * 512);
    dma16(Kb + ((size_t)(b * NN) + j0 + drow1) * DD + h * HDD + dcol, Ks + (w * 2 + 1) * 512);
    __syncthreads();
    float li = linv[h][wi0 + ln];
    bf16x8 qf[2];
    qf[0] = *(const bf16x8*)&Qs[(wi0 + ln) * 64 + g * 8];
    qf[1] = *(const bf16x8*)&Qs[(wi0 + ln) * 64 + 32 + g * 8];
#pragma unroll
    for (int jt = 0; jt < 4; ++jt) {
      f32x4 sacc = zero4;
#pragma unroll
      for (int kc = 0; kc < 2; ++kc) {
        bf16x8 af = *(const bf16x8*)&Ks[(jt * 16 + ln) * 64 + kc * 32 + g * 8];
        sacc = __builtin_amdgcn_mfma_f32_16x16x32_bf16(af, qf[kc], sacc, 0, 0, 0);
      }
      P[jt][0] += exp2f(sacc[0] * C1 + b2f(tlv[jt].x)) * li;
      P[jt][1] += exp2f(sacc[1] * C1 + b2f(tlv[jt].y)) * li;
      P[jt][2] += exp2f(sacc[2] * C1 + b2f(tlv[jt].z)) * li;
      P[jt][3] += exp2f(sacc[3] * C1 + b2f(tlv[jt].w)) * li;
    }
  }
  float hs = 0.f;
#pragma unroll
  for (int jt = 0; jt < 4; ++jt) {
#pragma unroll
    for (int r = 0; r < 4; ++r) {
      float p = fmaxf(P[jt][r] * (1.f / NHH), 1e-10f);
      hs -= p * logf(p);
    }
  }
  hs += __shfl_xor(hs, 16, 64);
  hs += __shfl_xor(hs, 32, 64);
  if (g == 0) atomicAdd(&Hacc[(size_t)b * NN + i0 + wi0 + ln], hs);
}

__global__ __launch_bounds__(256) void zero_hacc_kernel(float* __restrict__ Hacc) {
  Hacc[blockIdx.x * 256 + threadIdx.x] = 0.f;
}

__global__ __launch_bounds__(256) void cert_kernel(const float* __restrict__ Hacc,
                                                   const float* __restrict__ cert,
                                                   float* __restrict__ outc) {
  int idx = blockIdx.x * 256 + threadIdx.x;
  float H = Hacc[idx];
  float sg = 1.f / (1.f + expf(H - HMAXL));
  outc[idx] = fmaxf(cert[idx], sg);
}

// ---------------------------------------------------------------------------
extern "C" void kernel_launch(void* const* d_in, const int* in_sizes, int n_in,
                              void* d_out, int out_size, void* d_ws, size_t ws_size,
                              hipStream_t stream) {
  const float* data      = (const float*)d_in[0];
  const float* traj_pos  = (const float*)d_in[1];
  const float* traj_quat = (const float*)d_in[2];
  const float* certainty = (const float*)d_in[3];
  const float* Wq = (const float*)d_in[4];
  const float* bq = (const float*)d_in[5];
  const float* Wk = (const float*)d_in[6];
  const float* bk = (const float*)d_in[7];
  const float* Wv = (const float*)d_in[8];
  const float* bv = (const float*)d_in[9];
  const float* Wo = (const float*)d_in[10];
  const float* bo = (const float*)d_in[11];

  float* ws = (float*)d_ws;
  float* traj = ws + TRAJ_OFF;
  u16* tl    = (u16*)(ws + TL_OFF);
  u16* datab = (u16*)(ws + DATAB_OFF);
  u16* wqb   = (u16*)(ws + WQB_OFF);
  u16* wkb   = (u16*)(ws + WKB_OFF);
  u16* wvb   = (u16*)(ws + WVB_OFF);
  u16* wob   = (u16*)(ws + WOB_OFF);
  u16* Qb    = (u16*)(ws + QB_OFF);
  u16* Kb    = (u16*)(ws + KB_OFF);
  u16* VtT   = (u16*)(ws + VT_OFF);
  u16* AOb   = (u16*)(ws + AOB_OFF);
  float* Lv   = ws + LV_OFF;
  float* Hacc = ws + HACC_OFF;
  float* out  = (float*)d_out;
  float* outc = out + (size_t)NB * NN * DD;

  conv_data_kernel<<<2048, 256, 0, stream>>>(data, datab);
  conv_w_kernel<<<dim3(1024, 4), 256, 0, stream>>>(Wq, Wk, Wv, Wo, wqb, wkb, wvb, wob);
  traj_kernel<<<NN, 256, 0, stream>>>(traj_pos, traj_quat, traj, tl);
  zero_hacc_kernel<<<(NB * NN) / 256, 256, 0, stream>>>(Hacc);
  gemm_qkv_kernel<<<dim3(16, 16, 3), 256, 0, stream>>>(datab, wqb, wkb, wvb, bq, bk, bv,
                                                       Qb, Kb, VtT);
  att_kernel<<<dim3(NN / 64, NB * NHH), 256, 0, stream>>>(Qb, Kb, VtT, tl, AOb, Lv);
  ent_kernel<<<dim3(NN / 64, NN / 64, NB), 256, 0, stream>>>(Qb, Kb, tl, Lv, Hacc);
  cert_kernel<<<(NB * NN) / 256, 256, 0, stream>>>(Hacc, certainty, outc);
  gemm_o_kernel<<<dim3(16, 16), 256, 0, stream>>>(AOb, wob, bo, out);
}

// Round 4
// 232.180 us; speedup vs baseline: 3.3021x; 1.0423x over previous
//
#include <hip/hip_runtime.h>
#include <math.h>

#define NB 2
#define NN 1024
#define DD 1024
#define NHH 16
#define HDD 64
#define BTT 20

typedef unsigned short u16;
typedef short bf16x8 __attribute__((ext_vector_type(8)));
typedef float f32x4 __attribute__((ext_vector_type(4)));

#define HMAXL 6.93147180559945f
#define C1 0.18033688011112042f   // 0.125 * log2(e)
#define TLC 0.72134752044448170f  // 0.5 * log2(e)
#define KC  0.072134752044448170f // log2(e) / 20

// ws offsets in floats
#define TRAJ_OFF 0          // unnormalized w, fp32 N*N
#define TL_OFF    1048576   // N*N bf16 -> 524288 float slots
#define DATAB_OFF 1572864
#define WQB_OFF   2621440
#define WKB_OFF   3145728
#define WVB_OFF   3670016
#define WOB_OFF   4194304
#define QB_OFF    4718592
#define KB_OFF    5767168
#define VT_OFF    6815744
#define AOB_OFF   7864320
#define LV_OFF    8912896   // 32768 f
#define HACC_OFF  8945664   // 2048 f
#define RS_OFF    8947712   // 1024 f (traj row sums)

__device__ __forceinline__ float b2f(u16 h) { return __uint_as_float(((unsigned)h) << 16); }
__device__ __forceinline__ u16 f2bf(float f) {
  unsigned u = __float_as_uint(f);
  return (u16)((u + 0x7fffu + ((u >> 16) & 1u)) >> 16);
}
__device__ __forceinline__ void dma16(const void* g, void* l) {
  __builtin_amdgcn_global_load_lds((const __attribute__((address_space(1))) void*)g,
                                   (__attribute__((address_space(3))) void*)l, 16, 0, 0);
}

// ---------------------------------------------------------------------------
__global__ __launch_bounds__(256) void conv_data_kernel(const float* __restrict__ src,
                                                        u16* __restrict__ dst) {
  int i = (blockIdx.x * 256 + threadIdx.x) * 4;
  float4 v = *(const float4*)(src + i);
  ushort4 o = {f2bf(v.x), f2bf(v.y), f2bf(v.z), f2bf(v.w)};
  *(ushort4*)(dst + i) = o;
}

__global__ __launch_bounds__(256) void conv_w_kernel(const float* __restrict__ w0,
                                                     const float* __restrict__ w1,
                                                     const float* __restrict__ w2,
                                                     const float* __restrict__ w3,
                                                     u16* __restrict__ d0, u16* __restrict__ d1,
                                                     u16* __restrict__ d2, u16* __restrict__ d3) {
  int z = blockIdx.y;
  const float* s = z == 0 ? w0 : (z == 1 ? w1 : (z == 2 ? w2 : w3));
  u16* d = z == 0 ? d0 : (z == 1 ? d1 : (z == 2 ? d2 : d3));
  int i = (blockIdx.x * 256 + threadIdx.x) * 4;
  float4 v = *(const float4*)(s + i);
  ushort4 o = {f2bf(v.x), f2bf(v.y), f2bf(v.z), f2bf(v.w)};
  *(ushort4*)(d + i) = o;
}

// ---------------------------------------------------------------------------
// Pass A: w[i][j] = exp(-mean_bt(||pi-pj|| + sqrt(2-2|qi.qj|))), row sums via atomics.
// Block: 8 i's (LDS-staged) x 256 j-lanes. Grid (4 j-tiles, 128 i-tiles).
// Uses unit-quaternion identity: min(||qi-qj||,||qi+qj||) = sqrt(2-2|dot|).
__global__ __launch_bounds__(256) void trajA_kernel(const float* __restrict__ pos,
                                                    const float* __restrict__ quat,
                                                    float* __restrict__ w,
                                                    float* __restrict__ rs) {
  const int tid = threadIdx.x;
  const int j = blockIdx.x * 256 + tid;
  const int i0 = blockIdx.y * 8;
  __shared__ float ld[8][BTT][8];  // [ii][bt][0..2]=pos, [4..7]=quat
  if (tid < 8 * BTT) {
    int ii = tid / BTT, bt = tid % BTT;
    const float* pp = pos + ((size_t)bt * NN + i0 + ii) * 3;
    ld[ii][bt][0] = pp[0]; ld[ii][bt][1] = pp[1]; ld[ii][bt][2] = pp[2];
    *(float4*)&ld[ii][bt][4] = *(const float4*)(quat + ((size_t)bt * NN + i0 + ii) * 4);
  }
  __syncthreads();
  float acc[8] = {};
  for (int bt = 0; bt < BTT; ++bt) {
    const float* pj = pos + ((size_t)bt * NN + j) * 3;
    float pjx = pj[0], pjy = pj[1], pjz = pj[2];
    float4 qj = *(const float4*)(quat + ((size_t)bt * NN + j) * 4);
#pragma unroll
    for (int ii = 0; ii < 8; ++ii) {
      float4 pi = *(const float4*)&ld[ii][bt][0];
      float4 qi = *(const float4*)&ld[ii][bt][4];
      float dx = pi.x - pjx, dy = pi.y - pjy, dz = pi.z - pjz;
      float d2 = fmaf(dz, dz, fmaf(dy, dy, dx * dx));
      float dot = fmaf(qi.w, qj.w, fmaf(qi.z, qj.z, fmaf(qi.y, qj.y, qi.x * qj.x)));
      float t = fmaf(-2.f, fabsf(dot), 2.f);
      acc[ii] += sqrtf(d2) + sqrtf(fmaxf(t, 0.f));
    }
  }
#pragma unroll
  for (int ii = 0; ii < 8; ++ii) {
    float v = exp2f(-acc[ii] * KC);
    w[(size_t)(i0 + ii) * NN + j] = v;
    float s = v;
#pragma unroll
    for (int off = 1; off < 64; off <<= 1) s += __shfl_xor(s, off, 64);
    if ((tid & 63) == 0) atomicAdd(&rs[i0 + ii], s);
  }
}

// Pass B: tl[i][j] = bf16(w[i][j] / rs[i] * 0.5 * log2e). Block per row.
__global__ __launch_bounds__(256) void trajB_kernel(const float* __restrict__ w,
                                                    const float* __restrict__ rs,
                                                    u16* __restrict__ tl) {
  const int i = blockIdx.x;
  const int tid = threadIdx.x;
  float inv = TLC / rs[i];
  float4 w4 = *(const float4*)(w + (size_t)i * NN + tid * 4);
  ushort4 o = {f2bf(w4.x * inv), f2bf(w4.y * inv), f2bf(w4.z * inv), f2bf(w4.w * inv)};
  *(ushort4*)(tl + (size_t)i * NN + tid * 4) = o;
}

// ---------------------------------------------------------------------------
// Fused QKV projection GEMM, bf16 MFMA. BM=128, BN=64, BK=32.
__global__ __launch_bounds__(256) void gemm_qkv_kernel(const u16* __restrict__ Ab,
                                                       const u16* __restrict__ Wq,
                                                       const u16* __restrict__ Wk,
                                                       const u16* __restrict__ Wv,
                                                       const float* __restrict__ bq,
                                                       const float* __restrict__ bk,
                                                       const float* __restrict__ bv,
                                                       u16* __restrict__ Qb,
                                                       u16* __restrict__ Kb,
                                                       u16* __restrict__ VtT) {
  const int z = blockIdx.z;
  const u16* Wb = z == 0 ? Wq : (z == 1 ? Wk : Wv);
  const float* bias = z == 0 ? bq : (z == 1 ? bk : bv);
  __shared__ __align__(16) u16 As[128 * 32];
  __shared__ __align__(16) u16 Ws[64 * 32];
  const int tid = threadIdx.x;
  const int w = tid >> 6, l = tid & 63, g = l >> 4, ln = l & 15;
  const int bm = blockIdx.y << 7, bn = blockIdx.x << 6;
  const int rowA0 = w * 32 + (l >> 2), rowA1 = rowA0 + 16;
  const int colA = (l & 3) * 8;
  const int rowB = w * 16 + (l >> 2);
  const u16* Aptr0 = Ab + (size_t)(bm + rowA0) * DD + colA;
  const u16* Aptr1 = Ab + (size_t)(bm + rowA1) * DD + colA;
  const u16* Bptr = Wb + (size_t)(bn + rowB) * DD + colA;
  u16* ldsA0 = As + (w * 2) * 512;
  u16* ldsA1 = As + (w * 2 + 1) * 512;
  u16* ldsB = Ws + w * 512;
  f32x4 zero4 = {0.f, 0.f, 0.f, 0.f};
  f32x4 acc[4][2];
#pragma unroll
  for (int mt = 0; mt < 4; ++mt) { acc[mt][0] = zero4; acc[mt][1] = zero4; }
  const int mlo = (w & 1) * 64, nlo = (w >> 1) * 32;
  for (int k0 = 0; k0 < DD; k0 += 32) {
    __syncthreads();
    dma16(Aptr0 + k0, ldsA0);
    dma16(Aptr1 + k0, ldsA1);
    dma16(Bptr + k0, ldsB);
    __syncthreads();
    bf16x8 bfr[2];
#pragma unroll
    for (int nt = 0; nt < 2; ++nt)
      bfr[nt] = *(const bf16x8*)&Ws[(nlo + nt * 16 + ln) * 32 + g * 8];
#pragma unroll
    for (int mt = 0; mt < 4; ++mt) {
      bf16x8 af = *(const bf16x8*)&As[(mlo + mt * 16 + ln) * 32 + g * 8];
#pragma unroll
      for (int nt = 0; nt < 2; ++nt)
        acc[mt][nt] = __builtin_amdgcn_mfma_f32_16x16x32_bf16(af, bfr[nt], acc[mt][nt], 0, 0, 0);
    }
  }
#pragma unroll
  for (int nt = 0; nt < 2; ++nt) {
    int n = bn + nlo + nt * 16 + ln;
    float bb = bias[n];
    if (z == 2) {
      int row = (((bm >> 10) << 4) + (n >> 6)) * 64 + (n & 63);
#pragma unroll
      for (int mt = 0; mt < 4; ++mt) {
        int tok = ((bm & 1023) + mlo + mt * 16 + g * 4);
        ushort4 pk = {f2bf(acc[mt][nt][0] + bb), f2bf(acc[mt][nt][1] + bb),
                      f2bf(acc[mt][nt][2] + bb), f2bf(acc[mt][nt][3] + bb)};
        *(ushort4*)(VtT + (size_t)row * NN + tok) = pk;
      }
    } else {
      u16* outp = z == 0 ? Qb : Kb;
#pragma unroll
      for (int mt = 0; mt < 4; ++mt) {
#pragma unroll
        for (int r = 0; r < 4; ++r) {
          int m = bm + mlo + mt * 16 + g * 4 + r;
          outp[(size_t)m * DD + n] = f2bf(acc[mt][nt][r] + bb);
        }
      }
    }
  }
}

// ---------------------------------------------------------------------------
__global__ __launch_bounds__(256) void gemm_o_kernel(const u16* __restrict__ Ab,
                                                     const u16* __restrict__ Wb,
                                                     const float* __restrict__ bias,
                                                     float* __restrict__ C) {
  __shared__ __align__(16) u16 As[128 * 32];
  __shared__ __align__(16) u16 Ws[64 * 32];
  const int tid = threadIdx.x;
  const int w = tid >> 6, l = tid & 63, g = l >> 4, ln = l & 15;
  const int bm = blockIdx.y << 7, bn = blockIdx.x << 6;
  const int rowA0 = w * 32 + (l >> 2), rowA1 = rowA0 + 16;
  const int colA = (l & 3) * 8;
  const int rowB = w * 16 + (l >> 2);
  const u16* Aptr0 = Ab + (size_t)(bm + rowA0) * DD + colA;
  const u16* Aptr1 = Ab + (size_t)(bm + rowA1) * DD + colA;
  const u16* Bptr = Wb + (size_t)(bn + rowB) * DD + colA;
  u16* ldsA0 = As + (w * 2) * 512;
  u16* ldsA1 = As + (w * 2 + 1) * 512;
  u16* ldsB = Ws + w * 512;
  f32x4 zero4 = {0.f, 0.f, 0.f, 0.f};
  f32x4 acc[4][2];
#pragma unroll
  for (int mt = 0; mt < 4; ++mt) { acc[mt][0] = zero4; acc[mt][1] = zero4; }
  const int mlo = (w & 1) * 64, nlo = (w >> 1) * 32;
  for (int k0 = 0; k0 < DD; k0 += 32) {
    __syncthreads();
    dma16(Aptr0 + k0, ldsA0);
    dma16(Aptr1 + k0, ldsA1);
    dma16(Bptr + k0, ldsB);
    __syncthreads();
    bf16x8 bfr[2];
#pragma unroll
    for (int nt = 0; nt < 2; ++nt)
      bfr[nt] = *(const bf16x8*)&Ws[(nlo + nt * 16 + ln) * 32 + g * 8];
#pragma unroll
    for (int mt = 0; mt < 4; ++mt) {
      bf16x8 af = *(const bf16x8*)&As[(mlo + mt * 16 + ln) * 32 + g * 8];
#pragma unroll
      for (int nt = 0; nt < 2; ++nt)
        acc[mt][nt] = __builtin_amdgcn_mfma_f32_16x16x32_bf16(af, bfr[nt], acc[mt][nt], 0, 0, 0);
    }
  }
#pragma unroll
  for (int nt = 0; nt < 2; ++nt) {
    int n = bn + nlo + nt * 16 + ln;
    float bb = bias[n];
#pragma unroll
    for (int mt = 0; mt < 4; ++mt) {
#pragma unroll
      for (int r = 0; r < 4; ++r) {
        int m = bm + mlo + mt * 16 + g * 4 + r;
        C[(size_t)m * DD + n] = acc[mt][nt][r] + bb;
      }
    }
  }
}

// ---------------------------------------------------------------------------
// MFMA flash attention per (b,h,i-tile 64). S^T = K Q^T; PV uses Vt.
__global__ __launch_bounds__(256) void att_kernel(const u16* __restrict__ Qb,
                                                  const u16* __restrict__ Kb,
                                                  const u16* __restrict__ VtT,
                                                  const u16* __restrict__ tl,
                                                  u16* __restrict__ AOb,
                                                  float* __restrict__ Lv) {
  const int tid = threadIdx.x;
  const int bh = blockIdx.y;
  const int b = bh >> 4, h = bh & 15;
  const int i0 = blockIdx.x << 6;
  const int w = tid >> 6, l = tid & 63, g = l >> 4, ln = l & 15;
  const int wi0 = w * 16;
  __shared__ __align__(16) u16 Qs[64 * 64];
  __shared__ __align__(16) u16 Ks[64 * 64];
  __shared__ __align__(16) u16 Vts[64 * 64];
  __shared__ __align__(16) u16 Pt[64 * 72];
  __shared__ float lsc[64];
  const int drow0 = w * 16 + (l >> 3), drow1 = drow0 + 8;
  const int dcol = (l & 7) * 8;
  dma16(Qb + ((size_t)(b * NN) + i0 + drow0) * DD + h * HDD + dcol, Qs + (w * 2) * 512);
  dma16(Qb + ((size_t)(b * NN) + i0 + drow1) * DD + h * HDD + dcol, Qs + (w * 2 + 1) * 512);
  const int ig = i0 + wi0 + ln;
  f32x4 zero4 = {0.f, 0.f, 0.f, 0.f};
  f32x4 oacc[4];
#pragma unroll
  for (int nt = 0; nt < 4; ++nt) oacc[nt] = zero4;
  float lacc = 0.f;
  for (int j0 = 0; j0 < NN; j0 += 64) {
    __syncthreads();
    dma16(Kb + ((size_t)(b * NN) + j0 + drow0) * DD + h * HDD + dcol, Ks + (w * 2) * 512);
    dma16(Kb + ((size_t)(b * NN) + j0 + drow1) * DD + h * HDD + dcol, Ks + (w * 2 + 1) * 512);
    dma16(VtT + ((size_t)(bh * 64) + drow0) * NN + j0 + dcol, Vts + (w * 2) * 512);
    dma16(VtT + ((size_t)(bh * 64) + drow1) * NN + j0 + dcol, Vts + (w * 2 + 1) * 512);
    ushort4 tlv[4];
#pragma unroll
    for (int jt = 0; jt < 4; ++jt)
      tlv[jt] = *(const ushort4*)(tl + (size_t)ig * NN + j0 + jt * 16 + g * 4);
    __syncthreads();
    bf16x8 qf[2];
    qf[0] = *(const bf16x8*)&Qs[(wi0 + ln) * 64 + g * 8];
    qf[1] = *(const bf16x8*)&Qs[(wi0 + ln) * 64 + 32 + g * 8];
    f32x4 sacc[4];
#pragma unroll
    for (int jt = 0; jt < 4; ++jt) {
      sacc[jt] = zero4;
#pragma unroll
      for (int kc = 0; kc < 2; ++kc) {
        bf16x8 af = *(const bf16x8*)&Ks[(jt * 16 + ln) * 64 + kc * 32 + g * 8];
        sacc[jt] = __builtin_amdgcn_mfma_f32_16x16x32_bf16(af, qf[kc], sacc[jt], 0, 0, 0);
      }
    }
#pragma unroll
    for (int jt = 0; jt < 4; ++jt) {
      float e0 = exp2f(sacc[jt][0] * C1 + b2f(tlv[jt].x));
      float e1 = exp2f(sacc[jt][1] * C1 + b2f(tlv[jt].y));
      float e2 = exp2f(sacc[jt][2] * C1 + b2f(tlv[jt].z));
      float e3 = exp2f(sacc[jt][3] * C1 + b2f(tlv[jt].w));
      lacc += (e0 + e1) + (e2 + e3);
      ushort4 pk = {f2bf(e0), f2bf(e1), f2bf(e2), f2bf(e3)};
      *(ushort4*)(Pt + (wi0 + ln) * 72 + jt * 16 + g * 4) = pk;
    }
    __syncthreads();
    bf16x8 pf[2];
    pf[0] = *(const bf16x8*)&Pt[(wi0 + ln) * 72 + g * 8];
    pf[1] = *(const bf16x8*)&Pt[(wi0 + ln) * 72 + 32 + g * 8];
#pragma unroll
    for (int nt = 0; nt < 4; ++nt) {
#pragma unroll
      for (int kc = 0; kc < 2; ++kc) {
        bf16x8 vf = *(const bf16x8*)&Vts[(nt * 16 + ln) * 64 + kc * 32 + g * 8];
        oacc[nt] = __builtin_amdgcn_mfma_f32_16x16x32_bf16(pf[kc], vf, oacc[nt], 0, 0, 0);
      }
    }
  }
  lacc += __shfl_xor(lacc, 16, 64);
  lacc += __shfl_xor(lacc, 32, 64);
  if (g == 0) {
    Lv[(size_t)bh * NN + i0 + wi0 + ln] = lacc;
    lsc[wi0 + ln] = 1.f / lacc;
  }
  __syncthreads();
#pragma unroll
  for (int nt = 0; nt < 4; ++nt) {
    int d = nt * 16 + ln;
#pragma unroll
    for (int r = 0; r < 4; ++r) {
      int i = wi0 + g * 4 + r;
      float v = oacc[nt][r] * lsc[i];
      AOb[((size_t)(b * NN) + i0 + i) * DD + h * HDD + d] = f2bf(v);
    }
  }
}

// ---------------------------------------------------------------------------
__global__ __launch_bounds__(256) void ent_kernel(const u16* __restrict__ Qb,
                                                  const u16* __restrict__ Kb,
                                                  const u16* __restrict__ tl,
                                                  const float* __restrict__ Lv,
                                                  float* __restrict__ Hacc) {
  const int tid = threadIdx.x;
  const int j0 = blockIdx.x << 6;
  const int i0 = blockIdx.y << 6;
  const int b = blockIdx.z;
  const int w = tid >> 6, l = tid & 63, g = l >> 4, ln = l & 15;
  const int wi0 = w * 16;
  __shared__ __align__(16) u16 Qs[64 * 64];
  __shared__ __align__(16) u16 Ks[64 * 64];
  __shared__ float linv[NHH][64];
#pragma unroll
  for (int rep = 0; rep < 4; ++rep) {
    int idx = tid + (rep << 8);
    int hh = idx >> 6, ii = idx & 63;
    linv[hh][ii] = 1.f / Lv[((size_t)((b << 4) + hh)) * NN + i0 + ii];
  }
  const int drow0 = w * 16 + (l >> 3), drow1 = drow0 + 8;
  const int dcol = (l & 7) * 8;
  const int ig = i0 + wi0 + ln;
  ushort4 tlv[4];
#pragma unroll
  for (int jt = 0; jt < 4; ++jt)
    tlv[jt] = *(const ushort4*)(tl + (size_t)ig * NN + j0 + jt * 16 + g * 4);
  float P[4][4] = {};
  f32x4 zero4 = {0.f, 0.f, 0.f, 0.f};
  for (int h = 0; h < NHH; ++h) {
    __syncthreads();
    dma16(Qb + ((size_t)(b * NN) + i0 + drow0) * DD + h * HDD + dcol, Qs + (w * 2) * 512);
    dma16(Qb + ((size_t)(b * NN) + i0 + drow1) * DD + h * HDD + dcol, Qs + (w * 2 + 1) * 512);
    dma16(Kb + ((size_t)(b * NN) + j0 + drow0) * DD + h * HDD + dcol, Ks + (w * 2) * 512);
    dma16(Kb + ((size_t)(b * NN) + j0 + drow1) * DD + h * HDD + dcol, Ks + (w * 2 + 1) * 512);
    __syncthreads();
    float li = linv[h][wi0 + ln];
    bf16x8 qf[2];
    qf[0] = *(const bf16x8*)&Qs[(wi0 + ln) * 64 + g * 8];
    qf[1] = *(const bf16x8*)&Qs[(wi0 + ln) * 64 + 32 + g * 8];
#pragma unroll
    for (int jt = 0; jt < 4; ++jt) {
      f32x4 sacc = zero4;
#pragma unroll
      for (int kc = 0; kc < 2; ++kc) {
        bf16x8 af = *(const bf16x8*)&Ks[(jt * 16 + ln) * 64 + kc * 32 + g * 8];
        sacc = __builtin_amdgcn_mfma_f32_16x16x32_bf16(af, qf[kc], sacc, 0, 0, 0);
      }
      P[jt][0] += exp2f(sacc[0] * C1 + b2f(tlv[jt].x)) * li;
      P[jt][1] += exp2f(sacc[1] * C1 + b2f(tlv[jt].y)) * li;
      P[jt][2] += exp2f(sacc[2] * C1 + b2f(tlv[jt].z)) * li;
      P[jt][3] += exp2f(sacc[3] * C1 + b2f(tlv[jt].w)) * li;
    }
  }
  float hs = 0.f;
#pragma unroll
  for (int jt = 0; jt < 4; ++jt) {
#pragma unroll
    for (int r = 0; r < 4; ++r) {
      float p = fmaxf(P[jt][r] * (1.f / NHH), 1e-10f);
      hs -= p * logf(p);
    }
  }
  hs += __shfl_xor(hs, 16, 64);
  hs += __shfl_xor(hs, 32, 64);
  if (g == 0) atomicAdd(&Hacc[(size_t)b * NN + i0 + wi0 + ln], hs);
}

__global__ __launch_bounds__(256) void zero_acc_kernel(float* __restrict__ p) {
  p[blockIdx.x * 256 + threadIdx.x] = 0.f;
}

__global__ __launch_bounds__(256) void cert_kernel(const float* __restrict__ Hacc,
                                                   const float* __restrict__ cert,
                                                   float* __restrict__ outc) {
  int idx = blockIdx.x * 256 + threadIdx.x;
  float H = Hacc[idx];
  float sg = 1.f / (1.f + expf(H - HMAXL));
  outc[idx] = fmaxf(cert[idx], sg);
}

// ---------------------------------------------------------------------------
extern "C" void kernel_launch(void* const* d_in, const int* in_sizes, int n_in,
                              void* d_out, int out_size, void* d_ws, size_t ws_size,
                              hipStream_t stream) {
  const float* data      = (const float*)d_in[0];
  const float* traj_pos  = (const float*)d_in[1];
  const float* traj_quat = (const float*)d_in[2];
  const float* certainty = (const float*)d_in[3];
  const float* Wq = (const float*)d_in[4];
  const float* bq = (const float*)d_in[5];
  const float* Wk = (const float*)d_in[6];
  const float* bk = (const float*)d_in[7];
  const float* Wv = (const float*)d_in[8];
  const float* bv = (const float*)d_in[9];
  const float* Wo = (const float*)d_in[10];
  const float* bo = (const float*)d_in[11];

  float* ws = (float*)d_ws;
  float* wtr  = ws + TRAJ_OFF;
  u16* tl    = (u16*)(ws + TL_OFF);
  u16* datab = (u16*)(ws + DATAB_OFF);
  u16* wqb   = (u16*)(ws + WQB_OFF);
  u16* wkb   = (u16*)(ws + WKB_OFF);
  u16* wvb   = (u16*)(ws + WVB_OFF);
  u16* wob   = (u16*)(ws + WOB_OFF);
  u16* Qb    = (u16*)(ws + QB_OFF);
  u16* Kb    = (u16*)(ws + KB_OFF);
  u16* VtT   = (u16*)(ws + VT_OFF);
  u16* AOb   = (u16*)(ws + AOB_OFF);
  float* Lv   = ws + LV_OFF;
  float* Hacc = ws + HACC_OFF;  // 2048 Hacc + 1024 rs zeroed together
  float* rs   = ws + RS_OFF;
  float* out  = (float*)d_out;
  float* outc = out + (size_t)NB * NN * DD;

  zero_acc_kernel<<<12, 256, 0, stream>>>(Hacc);  // Hacc (2048) + rs (1024)
  conv_data_kernel<<<2048, 256, 0, stream>>>(data, datab);
  conv_w_kernel<<<dim3(1024, 4), 256, 0, stream>>>(Wq, Wk, Wv, Wo, wqb, wkb, wvb, wob);
  trajA_kernel<<<dim3(4, 128), 256, 0, stream>>>(traj_pos, traj_quat, wtr, rs);
  trajB_kernel<<<NN, 256, 0, stream>>>(wtr, rs, tl);
  gemm_qkv_kernel<<<dim3(16, 16, 3), 256, 0, stream>>>(datab, wqb, wkb, wvb, bq, bk, bv,
                                                       Qb, Kb, VtT);
  att_kernel<<<dim3(NN / 64, NB * NHH), 256, 0, stream>>>(Qb, Kb, VtT, tl, AOb, Lv);
  ent_kernel<<<dim3(NN / 64, NN / 64, NB), 256, 0, stream>>>(Qb, Kb, tl, Lv, Hacc);
  cert_kernel<<<(NB * NN) / 256, 256, 0, stream>>>(Hacc, certainty, outc);
  gemm_o_kernel<<<dim3(16, 16), 256, 0, stream>>>(AOb, wob, bo, out);
}